// Round 2
// baseline (309.009 us; speedup 1.0000x reference)
//
#include <hip/hip_runtime.h>

#define NB 1024
#define NS 1024
#define NT 32
#define L2E 1.44269504088896340736f
#define LN2 0.69314718055994530942f

typedef short        bfrag  __attribute__((ext_vector_type(8)));   // 8 bf16 (4 VGPR)
typedef float        cfrag  __attribute__((ext_vector_type(16)));  // 16 f32 acc
typedef __bf16       bf16x2 __attribute__((ext_vector_type(2)));
typedef float        f32x8  __attribute__((ext_vector_type(8)));
typedef float        f32x4  __attribute__((ext_vector_type(4)));
typedef float        f32x2  __attribute__((ext_vector_type(2)));
typedef unsigned int u32;
typedef unsigned int u32x4  __attribute__((ext_vector_type(4)));

__device__ __forceinline__ float fexp2(float x){ return __builtin_amdgcn_exp2f(x); }
__device__ __forceinline__ float flog2(float x){ return __builtin_amdgcn_logf(x); }

// RNE pack (prologue only)
__device__ __forceinline__ u32 pkbf_rne(float a, float b){
    f32x2 t; t.x = a; t.y = b;
    return __builtin_bit_cast(u32, __builtin_convertvector(t, bf16x2));
}
// truncation pack: single v_perm_b32. low16 = bf16_trunc(a), high16 = bf16_trunc(b).
__device__ __forceinline__ u32 pkbf_t(float a, float b){
    return __builtin_amdgcn_perm(__builtin_bit_cast(u32, b),
                                 __builtin_bit_cast(u32, a), 0x07060302u);
}
__device__ __forceinline__ bfrag mk_afrag(f32x8 v){
    u32x4 r;
    r[0] = pkbf_rne(v[0], v[1]); r[1] = pkbf_rne(v[2], v[3]);
    r[2] = pkbf_rne(v[4], v[5]); r[3] = pkbf_rne(v[6], v[7]);
    return __builtin_bit_cast(bfrag, r);
}

// row-space involution applied implicitly by packing C/D straight into B regs:
// swaps row blocks [4..7]<->[8..11] and [20..23]<->[24..27].
__device__ __forceinline__ int rho(int k){
    int bb = (k >> 2) & 3;
    return (bb == 1 || bb == 2) ? (k ^ 12) : k;
}

template<int N> struct ic { static constexpr int value = N; };
union accu { cfrag c; f32x2 p[8]; };
union q4u  { f32x4 v; f32x2 p[2]; };

// ---------------- Phase 1: per-(batch,chunk) 32x32 transfer matrix + gold ----------
// M <- D_t * (E^T @ M) in rho-permuted row space (no cross-lane swap per step:
// C/D packs straight into the next B operand; A and the initial identity are
// statically rho-compensated; combine reads row n at slot rho(n)).
// Gold (emission + transition, t>=1) is fused: the emission value is already in
// a register (lane m == tag[t] keeps it); trans lookup is a half-uniform L1-hot
// load. Per-wave partial -> gpart[bc]; combine folds them (keeps atomics at 1024).
__global__ __launch_bounds__(256, 8) void crf_chunk(
    const float* __restrict__ logits, const float* __restrict__ trans,
    const int* __restrict__ tags, const int* __restrict__ lens,
    u32* __restrict__ wmat, float* __restrict__ woff, float* __restrict__ gpart)
{
    __shared__ __align__(16) float dscall[4 * 512];   // per-wave: 2 bufs x 8 steps x 32

    const int tid = threadIdx.x;
    const int wv  = tid >> 6, lt = tid & 63;
    const int m   = lt & 31,  h  = lt >> 5;
    const int bc  = blockIdx.x * 4 + wv;
    const int b   = bc >> 3,  c  = bc & 7;
    float* dsc = dscall + wv * 512;

    const float* base = logits + (size_t)b * NS * NT;
    const int    len  = lens[b];
    const int    tb   = b * NS;

    // A frags with rho-compensated k index: A'[m][k] = exp(trans[rho(k)][m])
    f32x8 Et0, Et1;
    #pragma unroll
    for (int j = 0; j < 8; j++){
        Et0[j] = fexp2(L2E * trans[rho(     8*h + j)*NT + m]);
        Et1[j] = fexp2(L2E * trans[rho(16 + 8*h + j)*NT + m]);
    }
    const bfrag A0f = mk_afrag(Et0);
    const bfrag A1f = mk_afrag(Et1);

    // B = rho-permuted identity (packed bf16): slot k holds row rho(k)
    u32x4 B0v, B1v;
    #pragma unroll
    for (int d = 0; d < 4; d++){
        int k0 = 8*h + 2*d;      u32 v = 0;
        if (rho(k0)     == m) v |= 0x3F80u;
        if (rho(k0 + 1) == m) v |= 0x3F800000u;
        B0v[d] = v;
        int k1 = 16 + 8*h + 2*d; v = 0;
        if (rho(k1)     == m) v |= 0x3F80u;
        if (rho(k1 + 1) == m) v |= 0x3F800000u;
        B1v[d] = v;
    }

    cfrag zacc;
    #pragma unroll
    for (int q = 0; q < 16; q++) zacc[q] = 0.0f;

    int   offi = 0;        // accumulated log2 scale (integer, wave-uniform)
    float exf  = 0.0f;     // deferred scale folded into next block's step-0 D
    float g    = 0.0f;     // gold partial (emission + trans, t in this chunk)
    const int tbeg = c*128 + 1;

    float eA[4], eB[4];

    auto issue = [&](float (&e)[4], int k){
        const int t0 = tbeg + k*8 + 4*h;
        #pragma unroll
        for (int i = 0; i < 4; i++){
            int t = t0 + i; t = t > (NS-1) ? (NS-1) : t;   // clamp c==7 tail
            e[i] = base[t*NT + m];
        }
    };
    auto commit = [&](float (&e)[4], int k){
        float* sp = dsc + (k & 1)*256 + (4*h)*32 + m;
        float a0 = (h == 0) ? -exf : 0.0f;
        sp[0]    = fexp2(fmaf(L2E, e[0], a0));
        sp[32]   = fexp2(L2E * e[1]);
        sp[64]   = fexp2(L2E * e[2]);
        sp[96]   = fexp2(L2E * e[3]);
        // fused gold: rows t0..t0+3 of this half. Exactly the lane m==tag[t]
        // owns the emission value e[i]; same predicate gates the trans term.
        const int t0 = tbeg + k*8 + 4*h;
        int tp = tags[tb + t0 - 1];                        // t0 >= 1 always
        #pragma unroll
        for (int i = 0; i < 4; i++){
            int t  = t0 + i;
            int tc = tags[tb + (t > (NS-1) ? (NS-1) : t)];
            float contrib = e[i] + trans[tp*NT + tc];
            if (t < len && m == tc) g += contrib;
            tp = tc;
        }
    };

    auto exref = [&](float ref)->int{
        u32 xb = __builtin_bit_cast(u32, ref);
        u32 xf = __builtin_amdgcn_readfirstlane(xb);
        int ex = (int)((xf >> 23) & 0xFFu) - 127;
        return ex < -120 ? -120 : (ex > 120 ? 120 : ex);
    };

    auto procN = [&](int k, bool defer, auto nstc){
        constexpr int NST = decltype(nstc)::value;
        const float* db = dsc + (k & 1)*256 + 4*h;
        #pragma unroll
        for (int i = 0; i < NST; i++){
            accu acc;
            acc.c = __builtin_amdgcn_mfma_f32_32x32x16_bf16(
                        A0f, __builtin_bit_cast(bfrag, B0v), zacc, 0, 0, 0);
            acc.c = __builtin_amdgcn_mfma_f32_32x32x16_bf16(
                        A1f, __builtin_bit_cast(bfrag, B1v), acc.c, 0, 0, 0);

            // D_t row scales (true row space; unaffected by rho)
            q4u d0, d1, d2, d3;
            d0.v = *(const f32x4*)(db + i*32 +  0);
            d1.v = *(const f32x4*)(db + i*32 +  8);
            d2.v = *(const f32x4*)(db + i*32 + 16);
            d3.v = *(const f32x4*)(db + i*32 + 24);
            acc.p[0] *= d0.p[0]; acc.p[1] *= d0.p[1];
            acc.p[2] *= d1.p[0]; acc.p[3] *= d1.p[1];
            acc.p[4] *= d2.p[0]; acc.p[5] *= d2.p[1];
            acc.p[6] *= d3.p[0]; acc.p[7] *= d3.p[1];

            if (i == 3){
                int ex = exref(fmaxf(acc.c[0], acc.c[8]));
                offi += ex;
                f32x2 s2;
                s2.x = s2.y = __builtin_bit_cast(float, (u32)(127 - ex) << 23);
                #pragma unroll
                for (int q = 0; q < 8; q++) acc.p[q] *= s2;
            }
            if (i == 7 && defer){
                int ex = exref(fmaxf(acc.c[0], acc.c[8]));
                offi += ex;
                exf = (float)ex;
            }

            // pack C/D straight into B regs (lane-local; applies rho implicitly)
            B0v[0] = pkbf_t(acc.c[0],  acc.c[1]);  B0v[1] = pkbf_t(acc.c[2],  acc.c[3]);
            B0v[2] = pkbf_t(acc.c[4],  acc.c[5]);  B0v[3] = pkbf_t(acc.c[6],  acc.c[7]);
            B1v[0] = pkbf_t(acc.c[8],  acc.c[9]);  B1v[1] = pkbf_t(acc.c[10], acc.c[11]);
            B1v[2] = pkbf_t(acc.c[12], acc.c[13]); B1v[3] = pkbf_t(acc.c[14], acc.c[15]);
        }
    };

    issue(eA, 0); commit(eA, 0);
    #pragma unroll 1
    for (int k = 0; k < 14; k += 2){
        issue(eB, k + 1);
        procN(k, true, ic<8>{});
        commit(eB, k + 1);
        issue(eA, k + 2);
        procN(k + 1, true, ic<8>{});
        commit(eA, k + 2);
    }
    issue(eB, 15);
    procN(14, true, ic<8>{});
    commit(eB, 15);
    if (c != 7) procN(15, false, ic<8>{});   // wave-uniform branch
    else        procN(15, false, ic<7>{});   // chunk 7 has 127 steps

    // store M~ = rho(M) in B-frag form: wmat[bc*512 + d*64 + lane]
    const size_t mb = (size_t)bc * 512;
    #pragma unroll
    for (int d = 0; d < 4; d++){
        wmat[mb + d*64 + lt]     = B0v[d];
        wmat[mb + (4+d)*64 + lt] = B1v[d];
    }
    if (lt == 0) woff[bc] = (float)offi;

    // gold partial: reduce 64 lanes, one store per wave (no global atomics here)
    #pragma unroll
    for (int d = 1; d < 64; d <<= 1) g += __shfl_xor(g, d, 64);
    if (lt == 0) gpart[bc] = g;
}

// ---------------- Phase 2: per-batch combine (logZ + gold fold) ----------------
__global__ __launch_bounds__(64) void crf_combine(
    const float* __restrict__ logits, const int* __restrict__ tags,
    const u32* __restrict__ wmat, const float* __restrict__ woff,
    const float* __restrict__ gpart, float* __restrict__ out)
{
    __shared__ __align__(16) float ldsU[NT];

    const int tid = threadIdx.x;
    const int m   = tid & 31;
    const int b   = blockIdx.x;
    const float* lgb = logits + (size_t)b * NS * NT;

    // t=0 gold emission (broadcast loads, all lanes same address)
    const int   tg0 = tags[(size_t)b * NS];
    const float e0  = lgb[tg0];

    // fold chunk gold partials (8 floats, broadcast)
    float4 gp0 = ((const float4*)(gpart + b*8))[0];
    float4 gp1 = ((const float4*)(gpart + b*8))[1];
    const float gsum = (gp0.x + gp0.y) + (gp0.z + gp0.w)
                     + (gp1.x + gp1.y) + (gp1.z + gp1.w);

    float offs[8];
    #pragma unroll
    for (int cc = 0; cc < 8; cc++) offs[cc] = woff[b*8 + cc];

    float v    = fexp2(L2E * lgb[m]);
    float voff = 0.0f;

    // stored matrices are rho-permuted in row space: row n lives at slot rho(n)
    const int n  = m;
    const int bb = (n >> 2) & 3;
    const int nn = (bb == 1 || bb == 2) ? (n ^ 12) : n;
    const int f  = nn >> 4;
    const int hh = (nn >> 3) & 1;
    const int di = f*4 + ((nn >> 1) & 3);
    const int lo = nn & 1;

    auto ldrow = [&](int cc, uint4 (&md)[8]){
        const uint4* mp = (const uint4*)(wmat + (size_t)(b*8 + cc)*512 + di*64 + hh*32);
        #pragma unroll
        for (int qq = 0; qq < 8; qq++) md[qq] = mp[qq];
    };

    uint4 mdA[8], mdB[8];
    ldrow(0, mdA);

    #pragma unroll
    for (int cc = 0; cc < 8; cc++){
        uint4 (&cur)[8] = (cc & 1) ? mdB : mdA;
        uint4 (&nxt)[8] = (cc & 1) ? mdA : mdB;
        if (cc < 7) ldrow(cc + 1, nxt);      // prefetch next round's matrix

        float w  = flog2(v) + offs[cc];      // per-element log2 magnitude
        float mw = w;
        #pragma unroll
        for (int d = 1; d <= 16; d <<= 1) mw = fmaxf(mw, __shfl_xor(mw, d, 64));
        float u = fexp2(w - mw);
        if (tid < 32) ldsU[m] = u;
        __syncthreads();

        float acc = 0.0f;
        #pragma unroll
        for (int qq = 0; qq < 8; qq++){
            uint4  md = cur[qq];
            float4 uu = ((const float4*)ldsU)[qq];
            float v0 = __builtin_bit_cast(float, lo ? (md.x & 0xFFFF0000u) : (md.x << 16));
            float v1 = __builtin_bit_cast(float, lo ? (md.y & 0xFFFF0000u) : (md.y << 16));
            float v2 = __builtin_bit_cast(float, lo ? (md.z & 0xFFFF0000u) : (md.z << 16));
            float v3 = __builtin_bit_cast(float, lo ? (md.w & 0xFFFF0000u) : (md.w << 16));
            acc = fmaf(v0, uu.x, acc);
            acc = fmaf(v1, uu.y, acc);
            acc = fmaf(v2, uu.z, acc);
            acc = fmaf(v3, uu.w, acc);
        }
        v = acc;
        voff += mw;
        __syncthreads();
    }

    float s = v;
    #pragma unroll
    for (int d = 1; d <= 16; d <<= 1) s += __shfl_xor(s, d, 64);   // sum over 32 tags
    if (tid == 0){
        float logz = LN2 * (voff + flog2(s));
        atomicAdd(out, (logz - gsum - e0) * (1.0f / (float)NB));
    }
}

extern "C" void kernel_launch(void* const* d_in, const int* in_sizes, int n_in,
                              void* d_out, int out_size, void* d_ws, size_t ws_size,
                              hipStream_t stream) {
    const float* logits = (const float*)d_in[0];
    const float* trans  = (const float*)d_in[1];
    const int*   tags   = (const int*)d_in[2];
    const int*   lens   = (const int*)d_in[3];

    u32*   wmat  = (u32*)d_ws;                       // 8192*512*4 = 16 MB
    float* woff  = (float*)(wmat + 8192*512);        // 8192 floats
    float* gpart = woff + 8192;                      // 8192 floats

    hipMemsetAsync(d_out, 0, sizeof(float), stream);
    crf_chunk  <<<2048, 256, 0, stream>>>(logits, trans, tags, lens, wmat, woff, gpart);
    crf_combine<<<1024,  64, 0, stream>>>(logits, tags, wmat, woff, gpart, (float*)d_out);
}

// Round 3
// 261.697 us; speedup vs baseline: 1.1808x; 1.1808x over previous
//
#include <hip/hip_runtime.h>

#define NB 1024
#define NS 1024
#define NT 32
#define L2E 1.44269504088896340736f
#define LN2 0.69314718055994530942f

typedef short        bfrag  __attribute__((ext_vector_type(8)));   // 8 bf16 (4 VGPR)
typedef float        cfrag  __attribute__((ext_vector_type(16)));  // 16 f32 acc
typedef __bf16       bf16x2 __attribute__((ext_vector_type(2)));
typedef float        f32x8  __attribute__((ext_vector_type(8)));
typedef float        f32x4  __attribute__((ext_vector_type(4)));
typedef float        f32x2  __attribute__((ext_vector_type(2)));
typedef unsigned int u32;
typedef unsigned int u32x4  __attribute__((ext_vector_type(4)));

__device__ __forceinline__ float fexp2(float x){ return __builtin_amdgcn_exp2f(x); }
__device__ __forceinline__ float flog2(float x){ return __builtin_amdgcn_logf(x); }

// RNE pack (prologue only)
__device__ __forceinline__ u32 pkbf_rne(float a, float b){
    f32x2 t; t.x = a; t.y = b;
    return __builtin_bit_cast(u32, __builtin_convertvector(t, bf16x2));
}
// truncation pack: single v_perm_b32. low16 = bf16_trunc(a), high16 = bf16_trunc(b).
__device__ __forceinline__ u32 pkbf_t(float a, float b){
    return __builtin_amdgcn_perm(__builtin_bit_cast(u32, b),
                                 __builtin_bit_cast(u32, a), 0x07060302u);
}
__device__ __forceinline__ bfrag mk_afrag(f32x8 v){
    u32x4 r;
    r[0] = pkbf_rne(v[0], v[1]); r[1] = pkbf_rne(v[2], v[3]);
    r[2] = pkbf_rne(v[4], v[5]); r[3] = pkbf_rne(v[6], v[7]);
    return __builtin_bit_cast(bfrag, r);
}

// row-space involution applied implicitly by packing C/D straight into B regs:
// swaps row blocks [4..7]<->[8..11] and [20..23]<->[24..27].
__device__ __forceinline__ int rho(int k){
    int bb = (k >> 2) & 3;
    return (bb == 1 || bb == 2) ? (k ^ 12) : k;
}

template<int N> struct ic { static constexpr int value = N; };
union accu { cfrag c; f32x2 p[8]; };
union q4u  { f32x4 v; f32x2 p[2]; };

// ---------------- Phase 1: per-(batch,chunk) 32x32 transfer matrix ----------------
// M <- D_t * (E^T @ M) in rho-permuted row space: C/D packs straight into the next
// B operand (lane-local, no cross-lane swap); A and the initial identity are
// statically rho-compensated; combine reads row n at slot rho(n).
// NO gold fusion here (round-2 lesson: tags/trans gathers in the hot loop spill).
__global__ __launch_bounds__(256, 8) void crf_chunk(
    const float* __restrict__ logits, const float* __restrict__ trans,
    u32* __restrict__ wmat, float* __restrict__ woff, float* __restrict__ outz)
{
    __shared__ __align__(16) float dscall[4 * 512];   // per-wave: 2 bufs x 8 steps x 32

    const int tid = threadIdx.x;
    const int wv  = tid >> 6, lt = tid & 63;
    const int m   = lt & 31,  h  = lt >> 5;
    const int bc  = blockIdx.x * 4 + wv;
    const int b   = bc >> 3,  c  = bc & 7;
    float* dsc = dscall + wv * 512;

    if (blockIdx.x == 0 && tid == 0) *outz = 0.0f;    // replaces memset dispatch

    const float* base = logits + (size_t)b * NS * NT;

    // A frags with rho-compensated k index: A'[m][k] = exp(trans[rho(k)][m])
    f32x8 Et0, Et1;
    #pragma unroll
    for (int j = 0; j < 8; j++){
        Et0[j] = fexp2(L2E * trans[rho(     8*h + j)*NT + m]);
        Et1[j] = fexp2(L2E * trans[rho(16 + 8*h + j)*NT + m]);
    }
    const bfrag A0f = mk_afrag(Et0);
    const bfrag A1f = mk_afrag(Et1);

    // B = rho-permuted identity (packed bf16): slot k holds row rho(k)
    u32x4 B0v, B1v;
    #pragma unroll
    for (int d = 0; d < 4; d++){
        int k0 = 8*h + 2*d;      u32 v = 0;
        if (rho(k0)     == m) v |= 0x3F80u;
        if (rho(k0 + 1) == m) v |= 0x3F800000u;
        B0v[d] = v;
        int k1 = 16 + 8*h + 2*d; v = 0;
        if (rho(k1)     == m) v |= 0x3F80u;
        if (rho(k1 + 1) == m) v |= 0x3F800000u;
        B1v[d] = v;
    }

    cfrag zacc;
    #pragma unroll
    for (int q = 0; q < 16; q++) zacc[q] = 0.0f;

    int   offi = 0;        // accumulated log2 scale (integer, wave-uniform)
    float exf  = 0.0f;     // deferred scale folded into next block's step-0 D
    const int tbeg = c*128 + 1;

    float eA[4], eB[4];

    auto issue = [&](float (&e)[4], int k){
        const int t0 = tbeg + k*8 + 4*h;
        #pragma unroll
        for (int i = 0; i < 4; i++){
            int t = t0 + i; t = t > (NS-1) ? (NS-1) : t;   // clamp c==7 tail
            e[i] = base[t*NT + m];
        }
    };
    auto commit = [&](float (&e)[4], int k){
        float* sp = dsc + (k & 1)*256 + (4*h)*32 + m;
        float a0 = (h == 0) ? -exf : 0.0f;
        sp[0]    = fexp2(fmaf(L2E, e[0], a0));
        sp[32]   = fexp2(L2E * e[1]);
        sp[64]   = fexp2(L2E * e[2]);
        sp[96]   = fexp2(L2E * e[3]);
    };

    auto exref = [&](float ref)->int{
        u32 xb = __builtin_bit_cast(u32, ref);
        u32 xf = __builtin_amdgcn_readfirstlane(xb);
        int ex = (int)((xf >> 23) & 0xFFu) - 127;
        return ex < -120 ? -120 : (ex > 120 ? 120 : ex);
    };

    auto procN = [&](int k, bool defer, auto nstc){
        constexpr int NST = decltype(nstc)::value;
        const float* db = dsc + (k & 1)*256 + 4*h;
        #pragma unroll
        for (int i = 0; i < NST; i++){
            accu acc;
            acc.c = __builtin_amdgcn_mfma_f32_32x32x16_bf16(
                        A0f, __builtin_bit_cast(bfrag, B0v), zacc, 0, 0, 0);
            acc.c = __builtin_amdgcn_mfma_f32_32x32x16_bf16(
                        A1f, __builtin_bit_cast(bfrag, B1v), acc.c, 0, 0, 0);

            // D_t row scales (true row space; unaffected by rho)
            q4u d0, d1, d2, d3;
            d0.v = *(const f32x4*)(db + i*32 +  0);
            d1.v = *(const f32x4*)(db + i*32 +  8);
            d2.v = *(const f32x4*)(db + i*32 + 16);
            d3.v = *(const f32x4*)(db + i*32 + 24);
            acc.p[0] *= d0.p[0]; acc.p[1] *= d0.p[1];
            acc.p[2] *= d1.p[0]; acc.p[3] *= d1.p[1];
            acc.p[4] *= d2.p[0]; acc.p[5] *= d2.p[1];
            acc.p[6] *= d3.p[0]; acc.p[7] *= d3.p[1];

            if (i == 3){
                int ex = exref(fmaxf(acc.c[0], acc.c[8]));
                offi += ex;
                f32x2 s2;
                s2.x = s2.y = __builtin_bit_cast(float, (u32)(127 - ex) << 23);
                #pragma unroll
                for (int q = 0; q < 8; q++) acc.p[q] *= s2;
            }
            if (i == 7 && defer){
                int ex = exref(fmaxf(acc.c[0], acc.c[8]));
                offi += ex;
                exf = (float)ex;
            }

            // pack C/D straight into B regs (lane-local; applies rho implicitly)
            B0v[0] = pkbf_t(acc.c[0],  acc.c[1]);  B0v[1] = pkbf_t(acc.c[2],  acc.c[3]);
            B0v[2] = pkbf_t(acc.c[4],  acc.c[5]);  B0v[3] = pkbf_t(acc.c[6],  acc.c[7]);
            B1v[0] = pkbf_t(acc.c[8],  acc.c[9]);  B1v[1] = pkbf_t(acc.c[10], acc.c[11]);
            B1v[2] = pkbf_t(acc.c[12], acc.c[13]); B1v[3] = pkbf_t(acc.c[14], acc.c[15]);
        }
    };

    issue(eA, 0); commit(eA, 0);
    #pragma unroll 1
    for (int k = 0; k < 14; k += 2){
        issue(eB, k + 1);
        procN(k, true, ic<8>{});
        commit(eB, k + 1);
        issue(eA, k + 2);
        procN(k + 1, true, ic<8>{});
        commit(eA, k + 2);
    }
    issue(eB, 15);
    procN(14, true, ic<8>{});
    commit(eB, 15);
    if (c != 7) procN(15, false, ic<8>{});   // wave-uniform branch
    else        procN(15, false, ic<7>{});   // chunk 7 has 127 steps

    // store M~ = rho(M) in B-frag form: wmat[bc*512 + d*64 + lane]
    const size_t mb = (size_t)bc * 512;
    #pragma unroll
    for (int d = 0; d < 4; d++){
        wmat[mb + d*64 + lt]     = B0v[d];
        wmat[mb + (4+d)*64 + lt] = B1v[d];
    }
    if (lt == 0) woff[bc] = (float)offi;
}

// ---------------- Phase 2: per-batch gold + combine (256 threads) ----------------
// 4 waves: stage tags+trans in LDS, wave-parallel gold gather (4 pos/thread),
// then ALL waves redundantly run the 8-round matvec (uniform control flow, so
// __syncthreads stays legal; redundant wmat loads are L2-hits). Register
// double-buffer prefetch hides the wmat load latency under the softmax reduce.
__global__ __launch_bounds__(256) void crf_combine(
    const float* __restrict__ logits, const float* __restrict__ trans,
    const int* __restrict__ tags, const int* __restrict__ lens,
    const u32* __restrict__ wmat, const float* __restrict__ woff,
    float* __restrict__ out)
{
    __shared__ __align__(16) float ldsT[NT*NT];
    __shared__ __align__(16) int   ldsTag[NS];
    __shared__ __align__(16) float ldsU[NT];
    __shared__ float red[4];

    const int tid = threadIdx.x;
    const int m   = tid & 31;
    const int b   = blockIdx.x;
    const int len = lens[b];
    const float* lgb = logits + (size_t)b * NS * NT;

    ((float4*)ldsT)[tid] = ((const float4*)trans)[tid];                    // 4 KB
    ((int4*)ldsTag)[tid] = ((const int4*)(tags + (size_t)b * NS))[tid];    // 4 KB
    __syncthreads();

    // ---- gold: 4 positions per thread (includes t=0 emission; trans gated t>=1)
    const int t0 = tid * 4;
    int4 tgv = ((const int4*)ldsTag)[tid];
    int  prv = ldsTag[tid == 0 ? 0 : t0 - 1];
    int tgs[5] = {prv, tgv.x, tgv.y, tgv.z, tgv.w};

    float g = 0.0f;
    #pragma unroll
    for (int i = 0; i < 4; i++){
        int t = t0 + i;
        if (t < len){
            float e  = lgb[t*NT + tgs[i+1]];
            float tr = (t >= 1) ? ldsT[tgs[i]*NT + tgs[i+1]] : 0.0f;
            g += e + tr;
        }
    }
    #pragma unroll
    for (int d = 1; d < 64; d <<= 1) g += __shfl_xor(g, d, 64);
    if ((tid & 63) == 0) red[tid >> 6] = g;
    __syncthreads();
    const float gsum = red[0] + red[1] + red[2] + red[3];

    // ---- logZ: 8 sequential chunk-matrix applications (redundant across waves)
    float offs[8];
    #pragma unroll
    for (int cc = 0; cc < 8; cc++) offs[cc] = woff[b*8 + cc];

    float v    = fexp2(L2E * lgb[m]);     // t=0 emission (logZ side)
    float voff = 0.0f;

    // stored matrices are rho-permuted in row space: row n lives at slot rho(n)
    const int n  = m;
    const int bb = (n >> 2) & 3;
    const int nn = (bb == 1 || bb == 2) ? (n ^ 12) : n;
    const int f  = nn >> 4;
    const int hh = (nn >> 3) & 1;
    const int di = f*4 + ((nn >> 1) & 3);
    const int lo = nn & 1;

    auto ldrow = [&](int cc, uint4 (&md)[8]){
        const uint4* mp = (const uint4*)(wmat + (size_t)(b*8 + cc)*512 + di*64 + hh*32);
        #pragma unroll
        for (int qq = 0; qq < 8; qq++) md[qq] = mp[qq];
    };

    uint4 mdA[8], mdB[8];
    ldrow(0, mdA);

    #pragma unroll
    for (int cc = 0; cc < 8; cc++){
        uint4 (&cur)[8] = (cc & 1) ? mdB : mdA;
        uint4 (&nxt)[8] = (cc & 1) ? mdA : mdB;
        if (cc < 7) ldrow(cc + 1, nxt);      // prefetch next round's matrix

        float w  = flog2(v) + offs[cc];      // per-element log2 magnitude
        float mw = w;
        #pragma unroll
        for (int d = 1; d <= 16; d <<= 1) mw = fmaxf(mw, __shfl_xor(mw, d, 64));
        float u = fexp2(w - mw);
        if (tid < 32) ldsU[m] = u;
        __syncthreads();

        float acc = 0.0f;
        #pragma unroll
        for (int qq = 0; qq < 8; qq++){
            uint4  md = cur[qq];
            float4 uu = ((const float4*)ldsU)[qq];
            float v0 = __builtin_bit_cast(float, lo ? (md.x & 0xFFFF0000u) : (md.x << 16));
            float v1 = __builtin_bit_cast(float, lo ? (md.y & 0xFFFF0000u) : (md.y << 16));
            float v2 = __builtin_bit_cast(float, lo ? (md.z & 0xFFFF0000u) : (md.z << 16));
            float v3 = __builtin_bit_cast(float, lo ? (md.w & 0xFFFF0000u) : (md.w << 16));
            acc = fmaf(v0, uu.x, acc);
            acc = fmaf(v1, uu.y, acc);
            acc = fmaf(v2, uu.z, acc);
            acc = fmaf(v3, uu.w, acc);
        }
        v = acc;
        voff += mw;
        __syncthreads();
    }

    float s = v;
    #pragma unroll
    for (int d = 1; d <= 16; d <<= 1) s += __shfl_xor(s, d, 64);   // sum over 32 tags
    if (tid == 0){
        float logz = LN2 * (voff + flog2(s));
        atomicAdd(out, (logz - gsum) * (1.0f / (float)NB));
    }
}

extern "C" void kernel_launch(void* const* d_in, const int* in_sizes, int n_in,
                              void* d_out, int out_size, void* d_ws, size_t ws_size,
                              hipStream_t stream) {
    const float* logits = (const float*)d_in[0];
    const float* trans  = (const float*)d_in[1];
    const int*   tags   = (const int*)d_in[2];
    const int*   lens   = (const int*)d_in[3];

    u32*   wmat = (u32*)d_ws;                        // 8192*512*4 = 16 MB
    float* woff = (float*)(wmat + 8192*512);         // 8192 floats

    crf_chunk  <<<2048, 256, 0, stream>>>(logits, trans, wmat, woff, (float*)d_out);
    crf_combine<<<1024, 256, 0, stream>>>(logits, trans, tags, lens, wmat, woff,
                                          (float*)d_out);
}